// Round 4
// baseline (148.582 us; speedup 1.0000x reference)
//
#include <hip/hip_runtime.h>
#include <hip/hip_bf16.h>

// Problem constants (fixed by setup_inputs)
#define B_ROWS 4096
#define N_COLS 16384   // B_s * topk
#define CDIM   128
#define NIDS   751
#define TEMP_INV 20.0f
#define ASCALE 28.853900817779268f  // 20 * log2(e): fold temp + ln->log2 into A
#define LN2 0.6931471805599453f

// lse tiling: BM=256 rows/block (4 waves x 4 row-frags of 16), BN=64 cols/step
#define BM 256
#define BN 64
#define NCHUNK 32
#define COLS_PER_CHUNK (N_COLS / NCHUNK)     // 512
#define STEPS (COLS_PER_CHUNK / BN)          // 8
#define LSE_BLOCKS ((B_ROWS / BM) * NCHUNK)  // 512 -> 2 blocks/CU
#define POS_BLOCKS (N_COLS / 256)            // 64
#define NTBL ((NIDS + 15) / 16)              // 47 label-ownership blocks

typedef __attribute__((ext_vector_type(8))) short short8;      // 8 bf16
typedef __attribute__((ext_vector_type(4))) float f32x4;
typedef __attribute__((ext_vector_type(4))) unsigned short u16x4;

#define AS1 __attribute__((address_space(1)))
#define AS3 __attribute__((address_space(3)))

__device__ __forceinline__ unsigned short f2bf(float x) {
  union { float f; unsigned u; } c; c.f = x;
  unsigned r = c.u + 0x7FFFu + ((c.u >> 16) & 1u);  // RNE
  return (unsigned short)(r >> 16);
}

// ---- prep: label tables (atomic-free, blocks 0..46) + cvt (rest) + acc/ctr zero ----
__global__ void prep_kernel(const float* __restrict__ feats, const float* __restrict__ fs,
                            const int* __restrict__ labels, const int* __restrict__ labels_s,
                            unsigned short* __restrict__ feats_bf, unsigned short* __restrict__ fs_bf,
                            float* __restrict__ Ftab, float* __restrict__ Pcnt,
                            float* __restrict__ acc) {
  const int bid = blockIdx.x;
  const int tid = threadIdx.x;
  if (bid < NTBL) {
    // per-block: own 16 labels; build row list; LDS-accumulate; write out
    __shared__ float Facc[16 * CDIM];   // 8 KB
    __shared__ int   list[2048];        // 8 KB (mean occupancy ~87)
    __shared__ float Pc[16];
    __shared__ int   cnt;
    const int lo_l = bid * 16;
    if (bid == 0 && tid < 4) acc[tid] = 0.f;   // zero acc[0..1] + ctr (acc[2])
    for (int i = tid; i < 16 * CDIM; i += 256) Facc[i] = 0.f;
    if (tid < 16) Pc[tid] = 0.f;
    if (tid == 0) cnt = 0;
    __syncthreads();
    for (int r = tid; r < B_ROWS; r += 256) {
      unsigned d = (unsigned)(labels[r] - lo_l);
      if (d < 16u) {
        int k = atomicAdd(&cnt, 1);
        if (k < 2048) list[k] = (r << 4) | (int)d;
      }
    }
    for (int r = tid; r < N_COLS; r += 256) {
      unsigned d = (unsigned)(labels_s[r] - lo_l);
      if (d < 16u) atomicAdd(&Pc[d], 1.0f);
    }
    __syncthreads();
    int n = min(cnt, 2048);
    int c = tid & 127;
    for (int k = tid >> 7; k < n; k += 2) {    // 2 rows in flight, LDS f32 atomics
      int e = list[k]; int r = e >> 4, ll = e & 15;
      atomicAdd(&Facc[ll * CDIM + c], feats[(size_t)r * CDIM + c]);
    }
    __syncthreads();
    for (int i = tid; i < 16 * CDIM; i += 256) {
      int gl = lo_l + (i >> 7);
      if (gl < NIDS) Ftab[(size_t)gl * CDIM + (i & 127)] = Facc[i];
    }
    if (tid < 16 && lo_l + tid < NIDS) Pcnt[lo_l + tid] = Pc[tid];
  } else {
    // cvt: feats*ASCALE -> bf16 ; fs -> bf16
    const int NF4 = B_ROWS * CDIM / 4;   // 131072
    int idx = (bid - NTBL) * 256 + tid;
    if (idx < NF4) {
      f32x4 v = ((const f32x4*)feats)[idx];
      u16x4 o = { f2bf(v[0] * ASCALE), f2bf(v[1] * ASCALE), f2bf(v[2] * ASCALE), f2bf(v[3] * ASCALE) };
      ((u16x4*)feats_bf)[idx] = o;
    } else {
      int j = idx - NF4;
      f32x4 v = ((const f32x4*)fs)[j];
      u16x4 o = { f2bf(v[0]), f2bf(v[1]), f2bf(v[2]), f2bf(v[3]) };
      ((u16x4*)fs_bf)[j] = o;
    }
  }
}

// ---- main: lse (blocks 0..511) + posdot (blocks 512..575) ----
__launch_bounds__(256, 2)
__global__ void main_kernel(const unsigned short* __restrict__ A,   // feats bf16 (pre-scaled)
                            const unsigned short* __restrict__ Bm,  // fs bf16
                            const float* __restrict__ fs32,
                            const int* __restrict__ labels_s,
                            const float* __restrict__ Ftab, const float* __restrict__ Pcnt,
                            float* __restrict__ pmL,     // [NCHUNK][B_ROWS] partial lse (log2)
                            float* __restrict__ acc) {
  __shared__ unsigned short lds[2][BN * CDIM];  // 2 x 16 KB
  __shared__ float wsum[4];
  const int tid = threadIdx.x;

  if (blockIdx.x >= LSE_BLOCKS) {
    // posdot: acc[1] += sum_j fs_j . F[ls_j] / P[ls_j]  (fp32 exact)
    int j = (blockIdx.x - LSE_BLOCKS) * 256 + tid;
    int l = labels_s[j];
    const f32x4* fr = (const f32x4*)(fs32 + (size_t)j * CDIM);
    const f32x4* Fr = (const f32x4*)(Ftab + (size_t)l * CDIM);
    float d = 0.f;
#pragma unroll
    for (int q = 0; q < CDIM / 4; ++q) {
      f32x4 a = fr[q], b = Fr[q];
      d += a[0] * b[0] + a[1] * b[1] + a[2] * b[2] + a[3] * b[3];
    }
    d /= Pcnt[l];
#pragma unroll
    for (int off = 1; off < 64; off <<= 1) d += __shfl_xor(d, off, 64);
    if ((tid & 63) == 0) wsum[tid >> 6] = d;
    __syncthreads();
    if (tid == 0) atomicAdd(&acc[1], wsum[0] + wsum[1] + wsum[2] + wsum[3]);
    return;
  }

  // lse: online log2-sum-exp2 of feats_scaled @ fs^T, PER-ROW (m,s) state
  const int wv = tid >> 6, ln = tid & 63;
  const int hi = ln >> 4, lo = ln & 15;
  const int ch = blockIdx.x & (NCHUNK - 1);
  const int rb = blockIdx.x >> 5;
  const int col_base = ch * COLS_PER_CHUNK;

  const unsigned short* aptr = A + (size_t)(rb * BM + wv * 64 + lo) * CDIM + hi * 8;
  short8 afr[4][4];  // [rg][kk]
#pragma unroll
  for (int rg = 0; rg < 4; ++rg)
#pragma unroll
    for (int kk = 0; kk < 4; ++kk)
      afr[rg][kk] = *(const short8*)(aptr + rg * 16 * CDIM + kk * 32);

  float m_[4][4], s_[4][4];  // per-row state (row = rg*16 + hi*4 + j)
#pragma unroll
  for (int rg = 0; rg < 4; ++rg)
#pragma unroll
    for (int j = 0; j < 4; ++j) { m_[rg][j] = -1e30f; s_[rg][j] = 0.f; }

  // Stage BN x CDIM tile; LDS linear dest, global src pre-swizzled (chunk ^ (row&15))
  auto stage = [&](int buf, int step) {
    const int c0 = col_base + step * BN;
    char* base = (char*)&lds[buf][0];
#pragma unroll
    for (int r = 0; r < 4; ++r) {
      int q = r * 256 + wv * 64 + ln;
      int row = q >> 4, cc = q & 15;
      int cs = cc ^ (row & 15);
      const unsigned short* src = Bm + (size_t)(c0 + row) * CDIM + cs * 8;
      __builtin_amdgcn_global_load_lds((AS1 const void*)src,
                                       (AS3 void*)(base + (size_t)(r * 256 + wv * 64) * 16),
                                       16, 0, 0);
    }
  };

  stage(0, 0);
  int cur = 0;
  for (int t = 0; t < STEPS; ++t) {
    if (t + 1 < STEPS) {
      stage(cur ^ 1, t + 1);                               // 4 new loads stay in flight
      asm volatile("s_waitcnt vmcnt(4)" ::: "memory");
    } else {
      asm volatile("s_waitcnt vmcnt(0)" ::: "memory");
    }
    __builtin_amdgcn_s_barrier();
    __builtin_amdgcn_sched_barrier(0);

    f32x4 accv[4][4];  // [rg][ct]; z = sim*20*log2e; row=rg*16+hi*4+j, col=ct*16+lo
#pragma unroll
    for (int ct = 0; ct < 4; ++ct) {
      const int rowT = ct * 16 + lo;
      short8 bf[4];
#pragma unroll
      for (int kk = 0; kk < 4; ++kk) {
        int qs = (kk * 4 + hi) ^ (rowT & 15);
        bf[kk] = *(const short8*)&lds[cur][rowT * CDIM + qs * 8];
      }
#pragma unroll
      for (int rg = 0; rg < 4; ++rg) {
        f32x4 c4 = {0.f, 0.f, 0.f, 0.f};
#pragma unroll
        for (int kk = 0; kk < 4; ++kk)
          c4 = __builtin_amdgcn_mfma_f32_16x16x32_bf16(afr[rg][kk], bf[kk], c4, 0, 0, 0);
        accv[rg][ct] = c4;
      }
    }

    // Per-ROW online LSE in log2 domain (no shared-max underflow hazard)
#pragma unroll
    for (int rg = 0; rg < 4; ++rg)
#pragma unroll
      for (int j = 0; j < 4; ++j) {
        float v0 = accv[rg][0][j], v1 = accv[rg][1][j];
        float v2 = accv[rg][2][j], v3 = accv[rg][3][j];
        float mx = fmaxf(fmaxf(v0, v1), fmaxf(v2, v3));
        float mn = fmaxf(m_[rg][j], mx);
        s_[rg][j] = s_[rg][j] * __builtin_amdgcn_exp2f(m_[rg][j] - mn)
                  + (__builtin_amdgcn_exp2f(v0 - mn) + __builtin_amdgcn_exp2f(v1 - mn))
                  + (__builtin_amdgcn_exp2f(v2 - mn) + __builtin_amdgcn_exp2f(v3 - mn));
        m_[rg][j] = mn;
      }

    __builtin_amdgcn_sched_barrier(0);
    __builtin_amdgcn_s_barrier();
    cur ^= 1;
  }

  // merge across the 16 lanes sharing hi (cols); xor 1,2,4,8 stay in-group
#pragma unroll
  for (int rg = 0; rg < 4; ++rg)
#pragma unroll
    for (int j = 0; j < 4; ++j) {
#pragma unroll
      for (int off = 1; off < 16; off <<= 1) {
        float mo = __shfl_xor(m_[rg][j], off, 64);
        float so = __shfl_xor(s_[rg][j], off, 64);
        float mn = fmaxf(m_[rg][j], mo);
        s_[rg][j] = s_[rg][j] * __builtin_amdgcn_exp2f(m_[rg][j] - mn)
                  + so * __builtin_amdgcn_exp2f(mo - mn);
        m_[rg][j] = mn;
      }
    }

  if (lo == 0) {
    int rbase = rb * BM + wv * 64 + hi * 4;
#pragma unroll
    for (int rg = 0; rg < 4; ++rg)
#pragma unroll
      for (int j = 0; j < 4; ++j) {
        int row = rbase + rg * 16 + j;
        // honest per-row partial lse (log2 domain); s >= 1 so log2 is safe
        pmL[(size_t)ch * B_ROWS + row] = m_[rg][j] + __log2f(s_[rg][j]);
      }
  }
}

// ---- combine: per-row lse over 32 chunk-partials; last block finalizes ----
__global__ void combine_kernel(const float* __restrict__ pmL,
                               float* __restrict__ acc,
                               float* __restrict__ out) {
  int row = blockIdx.x * blockDim.x + threadIdx.x;  // 16 blocks x 256
  float L[NCHUNK];
  float mg = -1e30f;
#pragma unroll
  for (int c = 0; c < NCHUNK; ++c) {
    L[c] = pmL[c * B_ROWS + row];
    mg = fmaxf(mg, L[c]);
  }
  float sg = 0.f;
#pragma unroll
  for (int c = 0; c < NCHUNK; ++c) sg += __builtin_amdgcn_exp2f(L[c] - mg);
  float lse = LN2 * mg + logf(sg);  // natural-log lse per row
#pragma unroll
  for (int off = 1; off < 64; off <<= 1) lse += __shfl_xor(lse, off, 64);
  __shared__ float wsum[4];
  if ((threadIdx.x & 63) == 0) wsum[threadIdx.x >> 6] = lse;
  __syncthreads();
  if (threadIdx.x == 0) {
    atomicAdd(&acc[0], wsum[0] + wsum[1] + wsum[2] + wsum[3]);
    __threadfence();
    unsigned old = atomicAdd((unsigned*)&acc[2], 1u);
    if (old == (B_ROWS / 256) - 1) {   // last block finalizes (coherent atomic reads)
      float a0 = atomicAdd(&acc[0], 0.f);
      float a1 = atomicAdd(&acc[1], 0.f);
      out[0] = (a0 - TEMP_INV * a1) * (1.0f / (float)B_ROWS);
    }
  }
}

extern "C" void kernel_launch(void* const* d_in, const int* in_sizes, int n_in,
                              void* d_out, int out_size, void* d_ws, size_t ws_size,
                              hipStream_t stream) {
  const float* feats   = (const float*)d_in[0];
  const float* feats_s = (const float*)d_in[1];   // [16384][128] flat
  const int* labels    = (const int*)d_in[2];
  const int* labels_s  = (const int*)d_in[3];
  float* out = (float*)d_out;

  char* ws = (char*)d_ws;
  size_t off = 0;
  auto carve = [&](size_t bytes) -> char* {
    char* p = ws + off;
    off += (bytes + 255) & ~(size_t)255;
    return p;
  };
  unsigned short* feats_bf = (unsigned short*)carve((size_t)B_ROWS * CDIM * 2);  // 1 MB
  unsigned short* fs_bf    = (unsigned short*)carve((size_t)N_COLS * CDIM * 2);  // 4 MB
  float* Ftab = (float*)carve((size_t)NIDS * CDIM * 4);                          // 384 KB
  float* Pcnt = (float*)carve((size_t)NIDS * 4);
  float* pmL  = (float*)carve((size_t)NCHUNK * B_ROWS * 4);                      // 512 KB
  float* acc  = (float*)carve(4 * 4);   // [0]=lse sum, [1]=pos sum, [2]=counter

  const int NCVT = (B_ROWS * CDIM / 4 + N_COLS * CDIM / 4) / 256;  // 2560
  prep_kernel<<<NTBL + NCVT, 256, 0, stream>>>(feats, feats_s, labels, labels_s,
                                               feats_bf, fs_bf, Ftab, Pcnt, acc);
  main_kernel<<<LSE_BLOCKS + POS_BLOCKS, 256, 0, stream>>>(feats_bf, fs_bf, feats_s, labels_s,
                                                           Ftab, Pcnt, pmL, acc);
  combine_kernel<<<B_ROWS / 256, 256, 0, stream>>>(pmL, acc, out);
}

// Round 5
// 106.720 us; speedup vs baseline: 1.3923x; 1.3923x over previous
//
#include <hip/hip_runtime.h>
#include <hip/hip_bf16.h>

// Problem constants (fixed by setup_inputs)
#define B_ROWS 4096
#define N_COLS 16384   // B_s * topk
#define CDIM   128
#define NIDS   751
#define TEMP_INV 20.0f
#define ASCALE 28.853900817779268f  // 20 * log2(e): fold temp + ln->log2 into A
#define LN2 0.6931471805599453f

// lse tiling: BM=256 rows/block (4 waves x 4 row-frags of 16), BN=64 cols/step
#define BM 256
#define BN 64
#define NCHUNK 32
#define COLS_PER_CHUNK (N_COLS / NCHUNK)     // 512
#define STEPS (COLS_PER_CHUNK / BN)          // 8
#define LSE_BLOCKS ((B_ROWS / BM) * NCHUNK)  // 512 -> 2 blocks/CU
#define POS_BLOCKS (N_COLS / 256)            // 64
#define NLBL NIDS                            // 751 per-label table blocks

typedef __attribute__((ext_vector_type(8))) short short8;      // 8 bf16
typedef __attribute__((ext_vector_type(4))) float f32x4;
typedef __attribute__((ext_vector_type(4))) unsigned short u16x4;

#define AS1 __attribute__((address_space(1)))
#define AS3 __attribute__((address_space(3)))

__device__ __forceinline__ unsigned short f2bf(float x) {
  union { float f; unsigned u; } c; c.f = x;
  unsigned r = c.u + 0x7FFFu + ((c.u >> 16) & 1u);  // RNE
  return (unsigned short)(r >> 16);
}

// ---- prep: per-label tables (blocks 0..750, no global atomics, no memset)
//            + cvt (blocks 751..) + acc/ctr zero ----
__global__ void prep_kernel(const float* __restrict__ feats, const float* __restrict__ fs,
                            const int* __restrict__ labels, const int* __restrict__ labels_s,
                            unsigned short* __restrict__ feats_bf, unsigned short* __restrict__ fs_bf,
                            float* __restrict__ Ftab, float* __restrict__ Pcnt,
                            float* __restrict__ acc) {
  const int bid = blockIdx.x;
  const int tid = threadIdx.x;
  if (bid < NLBL) {
    // block owns label `bid`: find rows of feats with labels==bid (avg ~5.5),
    // count labels_s==bid, gather-sum rows -> Ftab[bid], count -> Pcnt[bid].
    __shared__ int list[64];
    __shared__ int cnt;
    __shared__ float red[4];
    if (tid == 0) cnt = 0;
    if (bid == 0 && tid < 4) acc[tid] = 0.f;   // zero acc[0..1] + ctr
    __syncthreads();
    // scan labels (4096) via int4: 4 iters
    const int4* lab4 = (const int4*)labels;
#pragma unroll
    for (int it = 0; it < 4; ++it) {
      int idx = it * 256 + tid;
      int4 v = lab4[idx];
      int r0 = idx * 4;
      if (v.x == bid) { int k = atomicAdd(&cnt, 1); if (k < 64) list[k] = r0; }
      if (v.y == bid) { int k = atomicAdd(&cnt, 1); if (k < 64) list[k] = r0 + 1; }
      if (v.z == bid) { int k = atomicAdd(&cnt, 1); if (k < 64) list[k] = r0 + 2; }
      if (v.w == bid) { int k = atomicAdd(&cnt, 1); if (k < 64) list[k] = r0 + 3; }
    }
    // count labels_s (16384) via int4: 16 iters, register count
    const int4* ls4 = (const int4*)labels_s;
    int c = 0;
#pragma unroll 4
    for (int it = 0; it < 16; ++it) {
      int4 v = ls4[it * 256 + tid];
      c += (v.x == bid) + (v.y == bid) + (v.z == bid) + (v.w == bid);
    }
#pragma unroll
    for (int off = 1; off < 64; off <<= 1) c += __shfl_xor(c, off, 64);
    if ((tid & 63) == 0) red[tid >> 6] = (float)c;
    __syncthreads();
    int n = min(cnt, 64);
    if (tid < CDIM) {
      float a = 0.f;
      for (int k = 0; k < n; ++k) a += feats[(size_t)list[k] * CDIM + tid];
      Ftab[(size_t)bid * CDIM + tid] = a;
    } else if (tid == CDIM) {
      Pcnt[bid] = red[0] + red[1] + red[2] + red[3];
    }
  } else {
    // cvt: feats*ASCALE -> bf16 ; fs -> bf16
    const int NF4 = B_ROWS * CDIM / 4;   // 131072
    int idx = (bid - NLBL) * 256 + tid;
    if (idx < NF4) {
      f32x4 v = ((const f32x4*)feats)[idx];
      u16x4 o = { f2bf(v[0] * ASCALE), f2bf(v[1] * ASCALE), f2bf(v[2] * ASCALE), f2bf(v[3] * ASCALE) };
      ((u16x4*)feats_bf)[idx] = o;
    } else {
      int j = idx - NF4;
      f32x4 v = ((const f32x4*)fs)[j];
      u16x4 o = { f2bf(v[0]), f2bf(v[1]), f2bf(v[2]), f2bf(v[3]) };
      ((u16x4*)fs_bf)[j] = o;
    }
  }
}

// ---- main: lse (blocks 0..511) + posdot (blocks 512..575) ----
__launch_bounds__(256, 2)
__global__ void main_kernel(const unsigned short* __restrict__ A,   // feats bf16 (pre-scaled)
                            const unsigned short* __restrict__ Bm,  // fs bf16
                            const float* __restrict__ fs32,
                            const int* __restrict__ labels_s,
                            const float* __restrict__ Ftab, const float* __restrict__ Pcnt,
                            float* __restrict__ pmL,     // [NCHUNK][B_ROWS] partial lse (log2)
                            float* __restrict__ acc) {
  __shared__ unsigned short lds[2][BN * CDIM];  // 2 x 16 KB
  __shared__ float wsum[4];
  const int tid = threadIdx.x;

  if (blockIdx.x >= LSE_BLOCKS) {
    // posdot: acc[1] += sum_j fs_j . F[ls_j] / P[ls_j]  (fp32 exact)
    int j = (blockIdx.x - LSE_BLOCKS) * 256 + tid;
    int l = labels_s[j];
    const f32x4* fr = (const f32x4*)(fs32 + (size_t)j * CDIM);
    const f32x4* Fr = (const f32x4*)(Ftab + (size_t)l * CDIM);
    float d = 0.f;
#pragma unroll
    for (int q = 0; q < CDIM / 4; ++q) {
      f32x4 a = fr[q], b = Fr[q];
      d += a[0] * b[0] + a[1] * b[1] + a[2] * b[2] + a[3] * b[3];
    }
    d /= Pcnt[l];
#pragma unroll
    for (int off = 1; off < 64; off <<= 1) d += __shfl_xor(d, off, 64);
    if ((tid & 63) == 0) wsum[tid >> 6] = d;
    __syncthreads();
    if (tid == 0) atomicAdd(&acc[1], wsum[0] + wsum[1] + wsum[2] + wsum[3]);
    return;
  }

  // lse: online log2-sum-exp2 of feats_scaled @ fs^T, PER-ROW (m,s) state
  const int wv = tid >> 6, ln = tid & 63;
  const int hi = ln >> 4, lo = ln & 15;
  const int ch = blockIdx.x & (NCHUNK - 1);
  const int rb = blockIdx.x >> 5;
  const int col_base = ch * COLS_PER_CHUNK;

  const unsigned short* aptr = A + (size_t)(rb * BM + wv * 64 + lo) * CDIM + hi * 8;
  short8 afr[4][4];  // [rg][kk]
#pragma unroll
  for (int rg = 0; rg < 4; ++rg)
#pragma unroll
    for (int kk = 0; kk < 4; ++kk)
      afr[rg][kk] = *(const short8*)(aptr + rg * 16 * CDIM + kk * 32);

  float m_[4][4], s_[4][4];  // per-row state (row = rg*16 + hi*4 + j)
#pragma unroll
  for (int rg = 0; rg < 4; ++rg)
#pragma unroll
    for (int j = 0; j < 4; ++j) { m_[rg][j] = -1e30f; s_[rg][j] = 0.f; }

  // Stage BN x CDIM tile; LDS linear dest, global src pre-swizzled (chunk ^ (row&15))
  auto stage = [&](int buf, int step) {
    const int c0 = col_base + step * BN;
    char* base = (char*)&lds[buf][0];
#pragma unroll
    for (int r = 0; r < 4; ++r) {
      int q = r * 256 + wv * 64 + ln;
      int row = q >> 4, cc = q & 15;
      int cs = cc ^ (row & 15);
      const unsigned short* src = Bm + (size_t)(c0 + row) * CDIM + cs * 8;
      __builtin_amdgcn_global_load_lds((AS1 const void*)src,
                                       (AS3 void*)(base + (size_t)(r * 256 + wv * 64) * 16),
                                       16, 0, 0);
    }
  };

  stage(0, 0);
  int cur = 0;
  for (int t = 0; t < STEPS; ++t) {
    if (t + 1 < STEPS) {
      stage(cur ^ 1, t + 1);                               // 4 new loads stay in flight
      asm volatile("s_waitcnt vmcnt(4)" ::: "memory");
    } else {
      asm volatile("s_waitcnt vmcnt(0)" ::: "memory");
    }
    __builtin_amdgcn_s_barrier();
    __builtin_amdgcn_sched_barrier(0);

    f32x4 accv[4][4];  // [rg][ct]; z = sim*20*log2e; row=rg*16+hi*4+j, col=ct*16+lo
#pragma unroll
    for (int ct = 0; ct < 4; ++ct) {
      const int rowT = ct * 16 + lo;
      short8 bf[4];
#pragma unroll
      for (int kk = 0; kk < 4; ++kk) {
        int qs = (kk * 4 + hi) ^ (rowT & 15);
        bf[kk] = *(const short8*)&lds[cur][rowT * CDIM + qs * 8];
      }
#pragma unroll
      for (int rg = 0; rg < 4; ++rg) {
        f32x4 c4 = {0.f, 0.f, 0.f, 0.f};
#pragma unroll
        for (int kk = 0; kk < 4; ++kk)
          c4 = __builtin_amdgcn_mfma_f32_16x16x32_bf16(afr[rg][kk], bf[kk], c4, 0, 0, 0);
        accv[rg][ct] = c4;
      }
    }

    // Per-ROW online LSE in log2 domain (no shared-max underflow hazard)
#pragma unroll
    for (int rg = 0; rg < 4; ++rg)
#pragma unroll
      for (int j = 0; j < 4; ++j) {
        float v0 = accv[rg][0][j], v1 = accv[rg][1][j];
        float v2 = accv[rg][2][j], v3 = accv[rg][3][j];
        float mx = fmaxf(fmaxf(v0, v1), fmaxf(v2, v3));
        float mn = fmaxf(m_[rg][j], mx);
        s_[rg][j] = s_[rg][j] * __builtin_amdgcn_exp2f(m_[rg][j] - mn)
                  + (__builtin_amdgcn_exp2f(v0 - mn) + __builtin_amdgcn_exp2f(v1 - mn))
                  + (__builtin_amdgcn_exp2f(v2 - mn) + __builtin_amdgcn_exp2f(v3 - mn));
        m_[rg][j] = mn;
      }

    __builtin_amdgcn_sched_barrier(0);
    __builtin_amdgcn_s_barrier();
    cur ^= 1;
  }

  // merge across the 16 lanes sharing hi (cols); xor 1,2,4,8 stay in-group
#pragma unroll
  for (int rg = 0; rg < 4; ++rg)
#pragma unroll
    for (int j = 0; j < 4; ++j) {
#pragma unroll
      for (int off = 1; off < 16; off <<= 1) {
        float mo = __shfl_xor(m_[rg][j], off, 64);
        float so = __shfl_xor(s_[rg][j], off, 64);
        float mn = fmaxf(m_[rg][j], mo);
        s_[rg][j] = s_[rg][j] * __builtin_amdgcn_exp2f(m_[rg][j] - mn)
                  + so * __builtin_amdgcn_exp2f(mo - mn);
        m_[rg][j] = mn;
      }
    }

  if (lo == 0) {
    int rbase = rb * BM + wv * 64 + hi * 4;
#pragma unroll
    for (int rg = 0; rg < 4; ++rg)
#pragma unroll
      for (int j = 0; j < 4; ++j) {
        int row = rbase + rg * 16 + j;
        // honest per-row partial lse (log2 domain); s >= 1 so log2 is safe
        pmL[(size_t)ch * B_ROWS + row] = m_[rg][j] + __log2f(s_[rg][j]);
      }
  }
}

// ---- combine: per-row lse over 32 chunk-partials; last block finalizes ----
__global__ void combine_kernel(const float* __restrict__ pmL,
                               float* __restrict__ acc,
                               float* __restrict__ out) {
  int row = blockIdx.x * blockDim.x + threadIdx.x;  // 16 blocks x 256
  float L[NCHUNK];
  float mg = -1e30f;
#pragma unroll
  for (int c = 0; c < NCHUNK; ++c) {
    L[c] = pmL[c * B_ROWS + row];
    mg = fmaxf(mg, L[c]);
  }
  float sg = 0.f;
#pragma unroll
  for (int c = 0; c < NCHUNK; ++c) sg += __builtin_amdgcn_exp2f(L[c] - mg);
  float lse = LN2 * mg + logf(sg);  // natural-log lse per row
#pragma unroll
  for (int off = 1; off < 64; off <<= 1) lse += __shfl_xor(lse, off, 64);
  __shared__ float wsum[4];
  if ((threadIdx.x & 63) == 0) wsum[threadIdx.x >> 6] = lse;
  __syncthreads();
  if (threadIdx.x == 0) {
    atomicAdd(&acc[0], wsum[0] + wsum[1] + wsum[2] + wsum[3]);
    __threadfence();
    unsigned old = atomicAdd((unsigned*)&acc[2], 1u);
    if (old == (B_ROWS / 256) - 1) {   // last block finalizes (coherent atomic reads)
      float a0 = atomicAdd(&acc[0], 0.f);
      float a1 = atomicAdd(&acc[1], 0.f);
      out[0] = (a0 - TEMP_INV * a1) * (1.0f / (float)B_ROWS);
    }
  }
}

extern "C" void kernel_launch(void* const* d_in, const int* in_sizes, int n_in,
                              void* d_out, int out_size, void* d_ws, size_t ws_size,
                              hipStream_t stream) {
  const float* feats   = (const float*)d_in[0];
  const float* feats_s = (const float*)d_in[1];   // [16384][128] flat
  const int* labels    = (const int*)d_in[2];
  const int* labels_s  = (const int*)d_in[3];
  float* out = (float*)d_out;

  char* ws = (char*)d_ws;
  size_t off = 0;
  auto carve = [&](size_t bytes) -> char* {
    char* p = ws + off;
    off += (bytes + 255) & ~(size_t)255;
    return p;
  };
  unsigned short* feats_bf = (unsigned short*)carve((size_t)B_ROWS * CDIM * 2);  // 1 MB
  unsigned short* fs_bf    = (unsigned short*)carve((size_t)N_COLS * CDIM * 2);  // 4 MB
  float* Ftab = (float*)carve((size_t)NIDS * CDIM * 4);                          // 384 KB
  float* Pcnt = (float*)carve((size_t)NIDS * 4);
  float* pmL  = (float*)carve((size_t)NCHUNK * B_ROWS * 4);                      // 512 KB
  float* acc  = (float*)carve(4 * 4);   // [0]=lse sum, [1]=pos sum, [2]=counter

  const int NCVT = (B_ROWS * CDIM / 4 + N_COLS * CDIM / 4) / 256;  // 2560
  prep_kernel<<<NLBL + NCVT, 256, 0, stream>>>(feats, feats_s, labels, labels_s,
                                               feats_bf, fs_bf, Ftab, Pcnt, acc);
  main_kernel<<<LSE_BLOCKS + POS_BLOCKS, 256, 0, stream>>>(feats_bf, fs_bf, feats_s, labels_s,
                                                           Ftab, Pcnt, pmL, acc);
  combine_kernel<<<B_ROWS / 256, 256, 0, stream>>>(pmL, acc, out);
}